// Round 6
// baseline (1972.584 us; speedup 1.0000x reference)
//
#include <hip/hip_runtime.h>

#define NGRAPH 4096
#define NNODE  64
#define NDIM   128
#define NLAYER 3
#define PH 136   // sh pitch (bf16): 68 dwords === 4 mod 32 -> bank-uniform b128 row reads
#define PZ 72    // szT pitch: 36 dwords === 4 mod 32

typedef __attribute__((ext_vector_type(8))) short short8;
typedef __attribute__((ext_vector_type(4))) float f32x4;
typedef __bf16 bf16x2 __attribute__((ext_vector_type(2)));

union S8 { short8 s8; unsigned d[4]; };

static __device__ inline ushort f2bf(float f) {  // RNE fp32 -> bf16 (fallback path)
  unsigned u = __float_as_uint(f);
  u += 0x7FFF + ((u >> 16) & 1);
  return (ushort)(u >> 16);
}

// packed fp32x2 -> bf16x2 in one HW instr on gfx950 (v_cvt_pk_bf16_f32)
static __device__ inline unsigned pkbf(float x, float y) {
#if __has_builtin(__builtin_amdgcn_cvt_pk_bf16_f32)
  bf16x2 v = __builtin_amdgcn_cvt_pk_bf16_f32(x, y);
  return __builtin_bit_cast(unsigned, v);
#else
  return (unsigned)f2bf(x) | ((unsigned)f2bf(y) << 16);
#endif
}

// load 8 consecutive fp32 and pack to a bf16 MFMA fragment (one instr per 2 elems)
static __device__ inline short8 load_w_frag(const float* __restrict__ rowp) {
  float4 v0 = *(const float4*)(rowp);
  float4 v1 = *(const float4*)(rowp + 4);
  S8 u;
  u.d[0] = pkbf(v0.x, v0.y); u.d[1] = pkbf(v0.z, v0.w);
  u.d[2] = pkbf(v1.x, v1.y); u.d[3] = pkbf(v1.z, v1.w);
  return u.s8;
}

__global__ __launch_bounds__(256, 4) void mpnn_mfma(
    const int* __restrict__ fps, const float* __restrict__ adj,
    const float* __restrict__ emb, const float* __restrict__ W,
    const float* __restrict__ bias, float* __restrict__ out) {
  __shared__ __align__(16) ushort sh[NNODE * PH];   // h  bf16 [node][d]   17408 B
  __shared__ __align__(16) ushort szT[NDIM * PZ];   // zT bf16 [k|d][node] 18432 B

  const int g    = blockIdx.x;
  const int t    = threadIdx.x;
  const int w    = t >> 6;        // wave 0..3
  const int lane = t & 63;
  const int r    = lane & 15;     // MFMA row/col index
  const int q    = lane >> 4;     // quad 0..3
  const int n0   = w << 5;        // wave's 32-wide k_out slab (m1) == d slab (m2)

  // ---- gather h0 = bf16(emb[fps]) ----
  const int* fg = fps + g * NNODE;
#pragma unroll
  for (int it = 0; it < 8; ++it) {
    int idx = it * 256 + t;               // 2048 float4s
    int n = idx >> 5;
    int c = (idx & 31) << 2;
    float4 v = *(const float4*)(emb + fg[n] * NDIM + c);
    uint2 u = {pkbf(v.x, v.y), pkbf(v.z, v.w)};
    *(uint2*)(sh + n * PH + c) = u;
  }

  // ---- adjacency fragments -> registers: single bf16 of A' = I + A (32 VGPRs) ----
  const float* adjg = adj + (size_t)g * NNODE * NNODE;
  short8 fadj[4][2];
#pragma unroll
  for (int nt = 0; nt < 4; ++nt) {
    int row = nt * 16 + r;                // output node (B-frag column)
    const float* rp = adjg + row * NNODE;
#pragma unroll
    for (int kh = 0; kh < 2; ++kh) {
      int cb = kh * 32 + 8 * q;           // k (source node) base
      float4 v0 = *(const float4*)(rp + cb);
      float4 v1 = *(const float4*)(rp + cb + 4);
      float vv[8] = {v0.x, v0.y, v0.z, v0.w, v1.x, v1.y, v1.z, v1.w};
      if ((nt >> 1) == kh) {              // diagonal can only hit these tiles
#pragma unroll
        for (int j = 0; j < 8; ++j)
          if (row == cb + j) vv[j] += 1.0f;
      }
      S8 hi;
#pragma unroll
      for (int jp = 0; jp < 4; ++jp) hi.d[jp] = pkbf(vv[2 * jp], vv[2 * jp + 1]);
      fadj[nt][kh] = hi.s8;
    }
  }
  __syncthreads();

#pragma unroll
  for (int l = 0; l < NLAYER; ++l) {
    const float* Wl = W + l * NDIM * NDIM;
    const float* bl = bias + l * NDIM;

    // ---- m1: z[node][n0-slab] = relu(h * W^T + b)  (A = h rows, B = W rows fp32->bf16) ----
    f32x4 acc[4][2];
#pragma unroll
    for (int nt = 0; nt < 2; ++nt) {
      float bv = bl[n0 + nt * 16 + r];
#pragma unroll
      for (int mt = 0; mt < 4; ++mt) acc[mt][nt] = (f32x4){bv, bv, bv, bv};
    }
#pragma unroll
    for (int k0 = 0; k0 < NDIM; k0 += 32) {
      short8 bw0 = load_w_frag(Wl + (n0 + r) * NDIM + k0 + 8 * q);
      short8 bw1 = load_w_frag(Wl + (n0 + 16 + r) * NDIM + k0 + 8 * q);
#pragma unroll
      for (int mi = 0; mi < 4; ++mi) {
        int mt = (mi + w) & 3;            // stagger per wave: decorrelate LDS convoy
        short8 ah = *(const short8*)(sh + (mt * 16 + r) * PH + k0 + 8 * q);
        acc[mt][0] = __builtin_amdgcn_mfma_f32_16x16x32_bf16(ah, bw0, acc[mt][0], 0, 0, 0);
        acc[mt][1] = __builtin_amdgcn_mfma_f32_16x16x32_bf16(ah, bw1, acc[mt][1], 0, 0, 0);
      }
    }
    // relu -> bf16 -> szT[k_out][node]  (C-frag: 4 consecutive nodes per lane)
#pragma unroll
    for (int mt = 0; mt < 4; ++mt)
#pragma unroll
      for (int nt = 0; nt < 2; ++nt) {
        f32x4 a = acc[mt][nt];
        uint2 u = {pkbf(fmaxf(a[0], 0.f), fmaxf(a[1], 0.f)),
                   pkbf(fmaxf(a[2], 0.f), fmaxf(a[3], 0.f))};
        *(uint2*)(szT + (n0 + nt * 16 + r) * PZ + mt * 16 + 4 * q) = u;
      }

    // ---- m2: houtT[d in n0-slab][node] = zT * (I+A)^T  (A = own szT rows, B = reg adj) ----
    f32x4 acc2[2][4];
#pragma unroll
    for (int mt = 0; mt < 2; ++mt)
#pragma unroll
      for (int nt = 0; nt < 4; ++nt) acc2[mt][nt] = (f32x4){0.f, 0.f, 0.f, 0.f};
#pragma unroll
    for (int kh = 0; kh < 2; ++kh) {
#pragma unroll
      for (int mt = 0; mt < 2; ++mt) {
        short8 az = *(const short8*)(szT + (n0 + mt * 16 + r) * PZ + kh * 32 + 8 * q);
#pragma unroll
        for (int nt = 0; nt < 4; ++nt)
          acc2[mt][nt] = __builtin_amdgcn_mfma_f32_16x16x32_bf16(az, fadj[nt][kh], acc2[mt][nt], 0, 0, 0);
      }
    }

    if (l < NLAYER - 1) {
      __syncthreads();   // all waves done reading sh (m1 A-frags)
#pragma unroll
      for (int mt = 0; mt < 2; ++mt)
#pragma unroll
        for (int nt = 0; nt < 4; ++nt) {
          f32x4 a = acc2[mt][nt];
          uint2 u = {pkbf(a[0], a[1]), pkbf(a[2], a[3])};
          *(uint2*)(sh + (nt * 16 + r) * PH + n0 + mt * 16 + 4 * q) = u;
        }
      __syncthreads();   // sh ready for next layer
    } else {
      // ---- sum-pool from C-frags: out[g][d] = sum_node houtT[d][node] ----
#pragma unroll
      for (int mt = 0; mt < 2; ++mt) {
        f32x4 s;
#pragma unroll
        for (int i = 0; i < 4; ++i)
          s[i] = acc2[mt][0][i] + acc2[mt][1][i] + acc2[mt][2][i] + acc2[mt][3][i];
#pragma unroll
        for (int m = 1; m <= 8; m <<= 1) {
          s[0] += __shfl_xor(s[0], m);
          s[1] += __shfl_xor(s[1], m);
          s[2] += __shfl_xor(s[2], m);
          s[3] += __shfl_xor(s[3], m);
        }
        if (r == 0) {
          float4 o = {s[0], s[1], s[2], s[3]};
          *(float4*)(out + (size_t)g * NDIM + n0 + mt * 16 + 4 * q) = o;
        }
      }
    }
  }
}

extern "C" void kernel_launch(void* const* d_in, const int* in_sizes, int n_in,
                              void* d_out, int out_size, void* d_ws, size_t ws_size,
                              hipStream_t stream) {
  const int*   fps  = (const int*)d_in[0];
  const float* adj  = (const float*)d_in[1];
  const float* emb  = (const float*)d_in[2];
  const float* W    = (const float*)d_in[3];
  const float* bias = (const float*)d_in[4];
  float* out = (float*)d_out;

  hipLaunchKernelGGL(mpnn_mfma, dim3(NGRAPH), dim3(256), 0, stream,
                     fps, adj, emb, W, bias, out);
}

// Round 7
// 218.751 us; speedup vs baseline: 9.0175x; 9.0175x over previous
//
#include <hip/hip_runtime.h>

#define NGRAPH 4096
#define NNODE  64
#define NDIM   128
#define NLAYER 3
#define PH 136   // sh pitch (bf16): 68 dwords === 4 mod 32 -> bank-uniform b128 row reads
#define PZ 72    // szT pitch: 36 dwords === 4 mod 32

typedef __attribute__((ext_vector_type(8))) short short8;
typedef __attribute__((ext_vector_type(4))) float f32x4;
typedef __bf16 bf16x2 __attribute__((ext_vector_type(2)));

union S8 { short8 s8; unsigned d[4]; };

static __device__ inline ushort f2bf(float f) {  // RNE fp32 -> bf16 (fallback path)
  unsigned u = __float_as_uint(f);
  u += 0x7FFF + ((u >> 16) & 1);
  return (ushort)(u >> 16);
}

// packed fp32x2 -> bf16x2 in one HW instr on gfx950 (v_cvt_pk_bf16_f32)
static __device__ inline unsigned pkbf(float x, float y) {
#if __has_builtin(__builtin_amdgcn_cvt_pk_bf16_f32)
  bf16x2 v = __builtin_amdgcn_cvt_pk_bf16_f32(x, y);
  return __builtin_bit_cast(unsigned, v);
#else
  return (unsigned)f2bf(x) | ((unsigned)f2bf(y) << 16);
#endif
}

// load 8 consecutive fp32, pack to bf16 MFMA fragment; fp32 temps die immediately
static __device__ inline short8 load_w_frag(const float* __restrict__ rowp) {
  float4 v0 = *(const float4*)(rowp);
  float4 v1 = *(const float4*)(rowp + 4);
  S8 u;
  u.d[0] = pkbf(v0.x, v0.y); u.d[1] = pkbf(v0.z, v0.w);
  u.d[2] = pkbf(v1.x, v1.y); u.d[3] = pkbf(v1.z, v1.w);
  return u.s8;
}

__global__ __launch_bounds__(256, 4) void mpnn_mfma(
    const int* __restrict__ fps, const float* __restrict__ adj,
    const float* __restrict__ emb, const float* __restrict__ W,
    const float* __restrict__ bias, float* __restrict__ out) {
  __shared__ __align__(16) ushort sh[NNODE * PH];   // h  bf16 [node][d]   17408 B
  __shared__ __align__(16) ushort szT[NDIM * PZ];   // zT bf16 [k|d][node] 18432 B

  const int g    = blockIdx.x;
  const int t    = threadIdx.x;
  const int w    = t >> 6;        // wave 0..3
  const int lane = t & 63;
  const int r    = lane & 15;     // MFMA row/col index
  const int q    = lane >> 4;     // quad 0..3
  const int n0   = w << 5;        // wave's 32-wide k_out slab (m1) == d slab (m2)

  // ---- gather h0 = bf16(emb[fps]) ----
  const int* fg = fps + g * NNODE;
#pragma unroll
  for (int it = 0; it < 8; ++it) {
    int idx = it * 256 + t;               // 2048 float4s
    int n = idx >> 5;
    int c = (idx & 31) << 2;
    float4 v = *(const float4*)(emb + fg[n] * NDIM + c);
    uint2 u = {pkbf(v.x, v.y), pkbf(v.z, v.w)};
    *(uint2*)(sh + n * PH + c) = u;
  }

  // ---- adjacency fragments -> registers: single bf16 of A' = I + A (32 VGPRs) ----
  const float* adjg = adj + (size_t)g * NNODE * NNODE;
  short8 fadj[4][2];
#pragma unroll
  for (int nt = 0; nt < 4; ++nt) {
    int row = nt * 16 + r;                // output node (B-frag column)
    const float* rp = adjg + row * NNODE;
#pragma unroll
    for (int kh = 0; kh < 2; ++kh) {
      int cb = kh * 32 + 8 * q;           // k (source node) base
      float4 v0 = *(const float4*)(rp + cb);
      float4 v1 = *(const float4*)(rp + cb + 4);
      float vv[8] = {v0.x, v0.y, v0.z, v0.w, v1.x, v1.y, v1.z, v1.w};
      if ((nt >> 1) == kh) {              // diagonal can only hit these tiles
#pragma unroll
        for (int j = 0; j < 8; ++j)
          if (row == cb + j) vv[j] += 1.0f;
      }
      S8 hi;
#pragma unroll
      for (int jp = 0; jp < 4; ++jp) hi.d[jp] = pkbf(vv[2 * jp], vv[2 * jp + 1]);
      fadj[nt][kh] = hi.s8;
    }
  }
  __syncthreads();

#pragma unroll 1   // real loop: keeps one layer's W temps live at a time (R6 spill fix)
  for (int l = 0; l < NLAYER; ++l) {
    const float* Wl = W + l * NDIM * NDIM;
    const float* bl = bias + l * NDIM;

    // ---- m1: z[node][n0-slab] = relu(h * W^T + b)  (A = h rows, B = W rows fp32->bf16) ----
    f32x4 acc[4][2];
#pragma unroll
    for (int nt = 0; nt < 2; ++nt) {
      float bv = bl[n0 + nt * 16 + r];
#pragma unroll
      for (int mt = 0; mt < 4; ++mt) acc[mt][nt] = (f32x4){bv, bv, bv, bv};
    }
#pragma unroll
    for (int k0 = 0; k0 < NDIM; k0 += 32) {
      short8 bw0 = load_w_frag(Wl + (n0 + r) * NDIM + k0 + 8 * q);
      short8 bw1 = load_w_frag(Wl + (n0 + 16 + r) * NDIM + k0 + 8 * q);
#pragma unroll
      for (int mt = 0; mt < 4; ++mt) {
        short8 ah = *(const short8*)(sh + (mt * 16 + r) * PH + k0 + 8 * q);
        acc[mt][0] = __builtin_amdgcn_mfma_f32_16x16x32_bf16(ah, bw0, acc[mt][0], 0, 0, 0);
        acc[mt][1] = __builtin_amdgcn_mfma_f32_16x16x32_bf16(ah, bw1, acc[mt][1], 0, 0, 0);
      }
    }
    // relu -> bf16 -> szT[k_out][node]  (C-frag: 4 consecutive nodes per lane)
#pragma unroll
    for (int mt = 0; mt < 4; ++mt)
#pragma unroll
      for (int nt = 0; nt < 2; ++nt) {
        f32x4 a = acc[mt][nt];
        uint2 u = {pkbf(fmaxf(a[0], 0.f), fmaxf(a[1], 0.f)),
                   pkbf(fmaxf(a[2], 0.f), fmaxf(a[3], 0.f))};
        *(uint2*)(szT + (n0 + nt * 16 + r) * PZ + mt * 16 + 4 * q) = u;
      }

    // ---- m2: houtT[d in n0-slab][node] = zT * (I+A)^T  (A = own szT rows, B = reg adj) ----
    f32x4 acc2[2][4];
#pragma unroll
    for (int mt = 0; mt < 2; ++mt)
#pragma unroll
      for (int nt = 0; nt < 4; ++nt) acc2[mt][nt] = (f32x4){0.f, 0.f, 0.f, 0.f};
#pragma unroll
    for (int kh = 0; kh < 2; ++kh) {
#pragma unroll
      for (int mt = 0; mt < 2; ++mt) {
        short8 az = *(const short8*)(szT + (n0 + mt * 16 + r) * PZ + kh * 32 + 8 * q);
#pragma unroll
        for (int nt = 0; nt < 4; ++nt)
          acc2[mt][nt] = __builtin_amdgcn_mfma_f32_16x16x32_bf16(az, fadj[nt][kh], acc2[mt][nt], 0, 0, 0);
      }
    }

    if (l < NLAYER - 1) {
      __syncthreads();   // all waves done reading sh (m1 A-frags)
#pragma unroll
      for (int mt = 0; mt < 2; ++mt)
#pragma unroll
        for (int nt = 0; nt < 4; ++nt) {
          f32x4 a = acc2[mt][nt];
          uint2 u = {pkbf(a[0], a[1]), pkbf(a[2], a[3])};
          *(uint2*)(sh + (nt * 16 + r) * PH + n0 + mt * 16 + 4 * q) = u;
        }
      __syncthreads();   // sh ready for next layer
    } else {
      // ---- sum-pool from C-frags: out[g][d] = sum_node houtT[d][node] ----
#pragma unroll
      for (int mt = 0; mt < 2; ++mt) {
        f32x4 s;
#pragma unroll
        for (int i = 0; i < 4; ++i)
          s[i] = acc2[mt][0][i] + acc2[mt][1][i] + acc2[mt][2][i] + acc2[mt][3][i];
#pragma unroll
        for (int m = 1; m <= 8; m <<= 1) {
          s[0] += __shfl_xor(s[0], m);
          s[1] += __shfl_xor(s[1], m);
          s[2] += __shfl_xor(s[2], m);
          s[3] += __shfl_xor(s[3], m);
        }
        if (r == 0) {
          float4 o = {s[0], s[1], s[2], s[3]};
          *(float4*)(out + (size_t)g * NDIM + n0 + mt * 16 + 4 * q) = o;
        }
      }
    }
  }
}

extern "C" void kernel_launch(void* const* d_in, const int* in_sizes, int n_in,
                              void* d_out, int out_size, void* d_ws, size_t ws_size,
                              hipStream_t stream) {
  const int*   fps  = (const int*)d_in[0];
  const float* adj  = (const float*)d_in[1];
  const float* emb  = (const float*)d_in[2];
  const float* W    = (const float*)d_in[3];
  const float* bias = (const float*)d_in[4];
  float* out = (float*)d_out;

  hipLaunchKernelGGL(mpnn_mfma, dim3(NGRAPH), dim3(256), 0, stream,
                     fps, adj, emb, W, bias, out);
}

// Round 8
// 175.003 us; speedup vs baseline: 11.2717x; 1.2500x over previous
//
#include <hip/hip_runtime.h>

#define NGRAPH 4096
#define NNODE  64
#define NDIM   128
#define NLAYER 3
#define PH 136   // sh pitch (bf16): 68 dwords === 4 mod 32 -> bank-uniform b128 row reads

typedef __attribute__((ext_vector_type(8))) short short8;
typedef __attribute__((ext_vector_type(4))) float f32x4;
typedef __bf16 bf16x2 __attribute__((ext_vector_type(2)));

union S8 { short8 s8; unsigned d[4]; };

static __device__ inline ushort f2bf(float f) {  // RNE fp32 -> bf16 (fallback path)
  unsigned u = __float_as_uint(f);
  u += 0x7FFF + ((u >> 16) & 1);
  return (ushort)(u >> 16);
}

// packed fp32x2 -> bf16x2 in one HW instr on gfx950 (v_cvt_pk_bf16_f32)
static __device__ inline unsigned pkbf(float x, float y) {
#if __has_builtin(__builtin_amdgcn_cvt_pk_bf16_f32)
  bf16x2 v = __builtin_amdgcn_cvt_pk_bf16_f32(x, y);
  return __builtin_bit_cast(unsigned, v);
#else
  return (unsigned)f2bf(x) | ((unsigned)f2bf(y) << 16);
#endif
}

// W in bf16, native [l][k_out][d] layout; tiny pre-kernel (GPU cost ~2 us, and the
// bench's ~70 us gap is harness-fixed regardless of dispatch count -- R7 evidence).
__device__ __align__(16) ushort g_wbf[NLAYER * NDIM * NDIM];

__global__ __launch_bounds__(256) void convert_w(const float* __restrict__ W) {
  int i = blockIdx.x * 256 + threadIdx.x;   // 192 blocks, exact
  g_wbf[i] = f2bf(W[i]);
}

__global__ __launch_bounds__(256, 4) void mpnn_mfma(
    const int* __restrict__ fps, const float* __restrict__ adj,
    const float* __restrict__ emb, const float* __restrict__ bias,
    float* __restrict__ out) {
  __shared__ __align__(16) ushort sh0[NNODE * PH];   // h ping  17408 B
  __shared__ __align__(16) ushort sh1[NNODE * PH];   // h pong  17408 B

  const int g    = blockIdx.x;
  const int t    = threadIdx.x;
  const int w    = t >> 6;        // wave 0..3
  const int lane = t & 63;
  const int r    = lane & 15;     // MFMA row/col index
  const int q    = lane >> 4;     // quad 0..3
  const int n0   = w << 5;        // wave's 32-wide k_out slab (m1) == d slab (m2)

  // bpermute addresses for the z C-frag -> A-frag quad permute (bytes; lane = addr/4)
  const int addr0 = (r + 32 * (q & 1)) << 2;   // source quads 0/2
  const int addr1 = addr0 + 64;                // source quads 1/3
  const bool hiQ  = (q >= 2);                  // dest q>>1 selects source mt register

  // ---- gather h0 = bf16(emb[fps]) into sh0 ----
  const int* fg = fps + g * NNODE;
#pragma unroll
  for (int it = 0; it < 8; ++it) {
    int idx = it * 256 + t;               // 2048 float4s
    int n = idx >> 5;
    int c = (idx & 31) << 2;
    float4 v = *(const float4*)(emb + fg[n] * NDIM + c);
    uint2 u = {pkbf(v.x, v.y), pkbf(v.z, v.w)};
    *(uint2*)(sh0 + n * PH + c) = u;
  }

  // ---- adjacency fragments -> registers: bf16 of A' = I + A (32 VGPRs) ----
  const float* adjg = adj + (size_t)g * NNODE * NNODE;
  short8 fadj[4][2];
#pragma unroll
  for (int nt = 0; nt < 4; ++nt) {
    int row = nt * 16 + r;                // output node (B-frag column)
    const float* rp = adjg + row * NNODE;
#pragma unroll
    for (int kh = 0; kh < 2; ++kh) {
      int cb = kh * 32 + 8 * q;           // k (source node) base
      float4 v0 = *(const float4*)(rp + cb);
      float4 v1 = *(const float4*)(rp + cb + 4);
      float vv[8] = {v0.x, v0.y, v0.z, v0.w, v1.x, v1.y, v1.z, v1.w};
      if ((nt >> 1) == kh) {              // diagonal can only hit these tiles
#pragma unroll
        for (int j = 0; j < 8; ++j)
          if (row == cb + j) vv[j] += 1.0f;
      }
      S8 hi;
#pragma unroll
      for (int jp = 0; jp < 4; ++jp) hi.d[jp] = pkbf(vv[2 * jp], vv[2 * jp + 1]);
      fadj[nt][kh] = hi.s8;
    }
  }

  // ---- bias for all layers -> registers (off the per-layer critical path) ----
  float bv[NLAYER][2];
#pragma unroll
  for (int l = 0; l < NLAYER; ++l)
#pragma unroll
    for (int nt = 0; nt < 2; ++nt) bv[l][nt] = bias[l * NDIM + n0 + nt * 16 + r];

  __syncthreads();

#pragma unroll 1   // real loop: avoid cross-layer load hoisting -> spill (R6 lesson)
  for (int l = 0; l < NLAYER; ++l) {
    const ushort* shr = (l & 1) ? sh1 : sh0;   // read buffer
    ushort*       shw = (l & 1) ? sh0 : sh1;   // write buffer (ping-pong)
    const ushort* Wl  = g_wbf + l * NDIM * NDIM;

    // ---- m1: z[node][n0-slab] = relu(h * W^T + b)  (A = h rows, B = W rows) ----
    f32x4 acc[4][2];
#pragma unroll
    for (int nt = 0; nt < 2; ++nt) {
      float b = bv[l][nt];
#pragma unroll
      for (int mt = 0; mt < 4; ++mt) acc[mt][nt] = (f32x4){b, b, b, b};
    }
#pragma unroll
    for (int k0 = 0; k0 < NDIM; k0 += 32) {
      short8 bw0 = *(const short8*)(Wl + (n0 + r) * NDIM + k0 + 8 * q);
      short8 bw1 = *(const short8*)(Wl + (n0 + 16 + r) * NDIM + k0 + 8 * q);
#pragma unroll
      for (int mt = 0; mt < 4; ++mt) {
        short8 ah = *(const short8*)(shr + (mt * 16 + r) * PH + k0 + 8 * q);
        acc[mt][0] = __builtin_amdgcn_mfma_f32_16x16x32_bf16(ah, bw0, acc[mt][0], 0, 0, 0);
        acc[mt][1] = __builtin_amdgcn_mfma_f32_16x16x32_bf16(ah, bw1, acc[mt][1], 0, 0, 0);
      }
    }
    // ---- relu -> packed bf16 in registers (no LDS round-trip) ----
    unsigned zc[4][2][2];   // [mt(node tile)][nt(=mt2 k_out tile)][x:nodes 4q+0,1 | y: 4q+2,3]
#pragma unroll
    for (int mt = 0; mt < 4; ++mt)
#pragma unroll
      for (int nt = 0; nt < 2; ++nt) {
        f32x4 a = acc[mt][nt];
        zc[mt][nt][0] = pkbf(fmaxf(a[0], 0.f), fmaxf(a[1], 0.f));
        zc[mt][nt][1] = pkbf(fmaxf(a[2], 0.f), fmaxf(a[3], 0.f));
      }

    // ---- m2: houtT[d in n0-slab][node] = zT * (I+A)^T ----
    // A-frag az assembled by quad-permute: dest (r,q) dword p pulls node pair
    // (kh*32+8q+2p, +1) from lane r+16*q', q' = 2(q&1)+(p>>1); register mt = 2kh+(q>>1).
    f32x4 acc2[2][4];
#pragma unroll
    for (int mt = 0; mt < 2; ++mt)
#pragma unroll
      for (int nt = 0; nt < 4; ++nt) acc2[mt][nt] = (f32x4){0.f, 0.f, 0.f, 0.f};
#pragma unroll
    for (int kh = 0; kh < 2; ++kh) {
#pragma unroll
      for (int mt2 = 0; mt2 < 2; ++mt2) {
        S8 az;
#pragma unroll
        for (int p = 0; p < 4; ++p) {
          int comp = p & 1;
          int lo = __builtin_amdgcn_ds_bpermute((p < 2) ? addr0 : addr1,
                                                (int)zc[2 * kh][mt2][comp]);
          int hi = __builtin_amdgcn_ds_bpermute((p < 2) ? addr0 : addr1,
                                                (int)zc[2 * kh + 1][mt2][comp]);
          az.d[p] = (unsigned)(hiQ ? hi : lo);
        }
#pragma unroll
        for (int nt = 0; nt < 4; ++nt)
          acc2[mt2][nt] = __builtin_amdgcn_mfma_f32_16x16x32_bf16(az.s8, fadj[nt][kh], acc2[mt2][nt], 0, 0, 0);
      }
    }

    if (l < NLAYER - 1) {
      // write h into the OTHER buffer: no pre-barrier needed (nobody reads shw now)
#pragma unroll
      for (int mt2 = 0; mt2 < 2; ++mt2)
#pragma unroll
        for (int nt = 0; nt < 4; ++nt) {
          f32x4 a = acc2[mt2][nt];
          uint2 u = {pkbf(a[0], a[1]), pkbf(a[2], a[3])};
          *(uint2*)(shw + (nt * 16 + r) * PH + n0 + mt2 * 16 + 4 * q) = u;
        }
      __syncthreads();   // single barrier per layer: shw visible to all
    } else {
      // ---- sum-pool from C-frags: out[g][d] = sum_node houtT[d][node] ----
#pragma unroll
      for (int mt2 = 0; mt2 < 2; ++mt2) {
        f32x4 s;
#pragma unroll
        for (int i = 0; i < 4; ++i)
          s[i] = acc2[mt2][0][i] + acc2[mt2][1][i] + acc2[mt2][2][i] + acc2[mt2][3][i];
#pragma unroll
        for (int m = 1; m <= 8; m <<= 1) {
          s[0] += __shfl_xor(s[0], m);
          s[1] += __shfl_xor(s[1], m);
          s[2] += __shfl_xor(s[2], m);
          s[3] += __shfl_xor(s[3], m);
        }
        if (r == 0) {
          float4 o = {s[0], s[1], s[2], s[3]};
          *(float4*)(out + (size_t)g * NDIM + n0 + mt2 * 16 + 4 * q) = o;
        }
      }
    }
  }
}

extern "C" void kernel_launch(void* const* d_in, const int* in_sizes, int n_in,
                              void* d_out, int out_size, void* d_ws, size_t ws_size,
                              hipStream_t stream) {
  const int*   fps  = (const int*)d_in[0];
  const float* adj  = (const float*)d_in[1];
  const float* emb  = (const float*)d_in[2];
  const float* W    = (const float*)d_in[3];
  const float* bias = (const float*)d_in[4];
  float* out = (float*)d_out;

  hipLaunchKernelGGL(convert_w, dim3(192), dim3(256), 0, stream, W);
  hipLaunchKernelGGL(mpnn_mfma, dim3(NGRAPH), dim3(256), 0, stream,
                     fps, adj, emb, bias, out);
}

// Round 9
// 163.242 us; speedup vs baseline: 12.0838x; 1.0720x over previous
//
#include <hip/hip_runtime.h>

#define NGRAPH 4096
#define NNODE  64
#define NDIM   128
#define NLAYER 3
#define PH 136   // sh pitch (bf16): 68 dwords === 4 mod 32 -> bank-uniform b128 row reads
#define PA 72    // sadj pitch: 36 dwords === 4 mod 32

typedef __attribute__((ext_vector_type(8))) short short8;
typedef __attribute__((ext_vector_type(4))) float f32x4;
typedef __bf16 bf16x2 __attribute__((ext_vector_type(2)));

union S8 { short8 s8; unsigned d[4]; };

static __device__ inline ushort f2bf(float f) {  // RNE fp32 -> bf16 (fallback path)
  unsigned u = __float_as_uint(f);
  u += 0x7FFF + ((u >> 16) & 1);
  return (ushort)(u >> 16);
}

// packed fp32x2 -> bf16x2 in one HW instr on gfx950 (v_cvt_pk_bf16_f32)
static __device__ inline unsigned pkbf(float x, float y) {
#if __has_builtin(__builtin_amdgcn_cvt_pk_bf16_f32)
  bf16x2 v = __builtin_amdgcn_cvt_pk_bf16_f32(x, y);
  return __builtin_bit_cast(unsigned, v);
#else
  return (unsigned)f2bf(x) | ((unsigned)f2bf(y) << 16);
#endif
}

// W in bf16, native [l][k_out][d] layout (B-frag reads W rows directly).
__device__ __align__(16) ushort g_wbf[NLAYER * NDIM * NDIM];

__global__ __launch_bounds__(256) void convert_w(const float* __restrict__ W) {
  int i = blockIdx.x * 256 + threadIdx.x;   // 192 blocks, exact
  g_wbf[i] = f2bf(W[i]);
}

__global__ __launch_bounds__(512, 6) void mpnn_mfma(
    const int* __restrict__ fps, const float* __restrict__ adj,
    const float* __restrict__ emb, const float* __restrict__ bias,
    float* __restrict__ out) {
  __shared__ __align__(16) ushort sh0[NNODE * PH];    // h ping  17408 B
  __shared__ __align__(16) ushort sh1[NNODE * PH];    // h pong  17408 B
  __shared__ __align__(16) ushort sadj[NNODE * PA];   // bf16(I+A)  9216 B

  const int g    = blockIdx.x;
  const int t    = threadIdx.x;
  const int w    = t >> 6;        // wave 0..7
  const int lane = t & 63;
  const int r    = lane & 15;     // MFMA row/col index
  const int q    = lane >> 4;     // quad 0..3
  const int n0   = w << 4;        // wave's 16-wide k_out slab (m1) == d slab (m2)

  // bpermute addresses for the z C-frag -> A-frag quad permute (R8-verified mapping)
  const int addr0 = (r + 32 * (q & 1)) << 2;   // p = 0,1
  const int addr1 = addr0 + 64;                // p = 2,3
  const bool hiQ  = (q >= 2);                  // source register select (node>=16 within 32)

  // ---- gather h0 = bf16(emb[fps]) into sh0 ----
  const int* fg = fps + g * NNODE;
#pragma unroll
  for (int it = 0; it < 4; ++it) {
    int idx = it * 512 + t;               // 2048 float4s
    int n = idx >> 5;
    int c = (idx & 31) << 2;
    float4 v = *(const float4*)(emb + fg[n] * NDIM + c);
    uint2 u = {pkbf(v.x, v.y), pkbf(v.z, v.w)};
    *(uint2*)(sh0 + n * PH + c) = u;
  }

  // ---- adjacency -> LDS: bf16(I + A), staged once per block ----
  const float* adjg = adj + (size_t)g * NNODE * NNODE;
#pragma unroll
  for (int it = 0; it < 2; ++it) {
    int idx = it * 512 + t;               // 1024 float4s
    int n = idx >> 4;
    int c = (idx & 15) << 2;
    float4 v = *(const float4*)(adjg + n * NNODE + c);
    v.x += (n == c + 0) ? 1.0f : 0.0f;    // fold residual: I + A
    v.y += (n == c + 1) ? 1.0f : 0.0f;
    v.z += (n == c + 2) ? 1.0f : 0.0f;
    v.w += (n == c + 3) ? 1.0f : 0.0f;
    uint2 u = {pkbf(v.x, v.y), pkbf(v.z, v.w)};
    *(uint2*)(sadj + n * PA + c) = u;
  }

  // ---- bias for all layers -> registers ----
  float bv[NLAYER];
#pragma unroll
  for (int l = 0; l < NLAYER; ++l) bv[l] = bias[l * NDIM + n0 + r];

  __syncthreads();

#pragma unroll 1   // real loop: avoid cross-layer load hoisting -> spill (R6 lesson)
  for (int l = 0; l < NLAYER; ++l) {
    const ushort* shr = (l & 1) ? sh1 : sh0;   // read buffer
    ushort*       shw = (l & 1) ? sh0 : sh1;   // write buffer (ping-pong)
    const ushort* Wl  = g_wbf + l * NDIM * NDIM;

    // ---- m1: z[node][n0-slab(16)] = relu(h * W^T + b) ----
    f32x4 acc[4];
#pragma unroll
    for (int mt = 0; mt < 4; ++mt) acc[mt] = (f32x4){bv[l], bv[l], bv[l], bv[l]};
#pragma unroll
    for (int k0 = 0; k0 < NDIM; k0 += 32) {
      short8 bw = *(const short8*)(Wl + (n0 + r) * NDIM + k0 + 8 * q);
#pragma unroll
      for (int mt = 0; mt < 4; ++mt) {
        short8 ah = *(const short8*)(shr + (mt * 16 + r) * PH + k0 + 8 * q);
        acc[mt] = __builtin_amdgcn_mfma_f32_16x16x32_bf16(ah, bw, acc[mt], 0, 0, 0);
      }
    }
    // ---- relu -> packed bf16 in registers ----
    unsigned zc[4][2];   // [mt: node tile][node pair within quad-rows]
#pragma unroll
    for (int mt = 0; mt < 4; ++mt) {
      f32x4 a = acc[mt];
      zc[mt][0] = pkbf(fmaxf(a[0], 0.f), fmaxf(a[1], 0.f));
      zc[mt][1] = pkbf(fmaxf(a[2], 0.f), fmaxf(a[3], 0.f));
    }

    // ---- m2: houtT[d in n0-slab][node'] = zT * (I+A)^T ----
    f32x4 acc2[4];
#pragma unroll
    for (int nt = 0; nt < 4; ++nt) acc2[nt] = (f32x4){0.f, 0.f, 0.f, 0.f};
#pragma unroll
    for (int kh = 0; kh < 2; ++kh) {
      S8 az;
#pragma unroll
      for (int p = 0; p < 4; ++p) {
        int comp = p & 1;
        int lo = __builtin_amdgcn_ds_bpermute((p < 2) ? addr0 : addr1,
                                              (int)zc[2 * kh][comp]);
        int hi = __builtin_amdgcn_ds_bpermute((p < 2) ? addr0 : addr1,
                                              (int)zc[2 * kh + 1][comp]);
        az.d[p] = (unsigned)(hiQ ? hi : lo);
      }
#pragma unroll
      for (int nt = 0; nt < 4; ++nt) {
        short8 fb = *(const short8*)(sadj + (nt * 16 + r) * PA + kh * 32 + 8 * q);
        acc2[nt] = __builtin_amdgcn_mfma_f32_16x16x32_bf16(az.s8, fb, acc2[nt], 0, 0, 0);
      }
    }

    if (l < NLAYER - 1) {
      // write h into the OTHER buffer: no pre-barrier needed
#pragma unroll
      for (int nt = 0; nt < 4; ++nt) {
        f32x4 a = acc2[nt];
        uint2 u = {pkbf(a[0], a[1]), pkbf(a[2], a[3])};
        *(uint2*)(shw + (nt * 16 + r) * PH + n0 + 4 * q) = u;
      }
      __syncthreads();   // single barrier per layer
    } else {
      // ---- sum-pool: out[g][d] = sum_node' h[node'][d] ----
      f32x4 s;
#pragma unroll
      for (int i = 0; i < 4; ++i)
        s[i] = acc2[0][i] + acc2[1][i] + acc2[2][i] + acc2[3][i];
#pragma unroll
      for (int m = 1; m <= 8; m <<= 1) {
        s[0] += __shfl_xor(s[0], m);
        s[1] += __shfl_xor(s[1], m);
        s[2] += __shfl_xor(s[2], m);
        s[3] += __shfl_xor(s[3], m);
      }
      if (r == 0) {
        float4 o = {s[0], s[1], s[2], s[3]};
        *(float4*)(out + (size_t)g * NDIM + n0 + 4 * q) = o;
      }
    }
  }
}

extern "C" void kernel_launch(void* const* d_in, const int* in_sizes, int n_in,
                              void* d_out, int out_size, void* d_ws, size_t ws_size,
                              hipStream_t stream) {
  const int*   fps  = (const int*)d_in[0];
  const float* adj  = (const float*)d_in[1];
  const float* emb  = (const float*)d_in[2];
  const float* W    = (const float*)d_in[3];
  const float* bias = (const float*)d_in[4];
  float* out = (float*)d_out;

  hipLaunchKernelGGL(convert_w, dim3(192), dim3(256), 0, stream, W);
  hipLaunchKernelGGL(mpnn_mfma, dim3(NGRAPH), dim3(512), 0, stream,
                     fps, adj, emb, bias, out);
}